// Round 2
// baseline (483.546 us; speedup 1.0000x reference)
//
#include <hip/hip_runtime.h>

// Morphological skeleton, 16 x 1024 x 1024 f32.
// skel = sum_{k=0..20} ( e_k - dilate3x3(e_{k+1}) ),  e_0 = x, e_{k+1} = erode3x3(e_k)
// (reduce_window SAME semantics: windows clamp at image borders).
//
// Register-resident vertical pipeline, zero LDS tile. 3 dispatches x G=7 fused
// erosion stages. One wave (64 lanes x float4) owns a 256-col band and sweeps
// RCH+16 rows (RCH output + warm-up/drain). Per stage: 2-row register buffer
// (parity-swapped); erode = v_min3 vertical + halo-register horizontal; dilate
// of f_s computed at iter s from the same rows; terms go into an 8-deep
// register FIFO, emitted as rows complete.
//
// Round-6 change vs round 5 (373 us): the DS pipe is the saturated resource.
// Round 4->5 doubled waves (+20% work) at IDENTICAL per-dispatch duration
// (108.5 -> 109.0 us): a shared-throughput bound whose demand didn't change =
// the 28 ds_bpermute/step (4 shuffles/stage: 2 erode-edge + 2 dilate-edge).
// Both edge values are vertical min/max over the SAME 3 rows at the neighbor
// column. New scheme: shuffle only the RAW new-row edges (cur.w / cur.x, 2
// bpermutes/stage), keep a 2-row register history of these halo scalars per
// stage, and compute the vertical min (erode) and max (dilate) locally. The
// dilate of f_s moves from iter s-1 to iter s (where f_s's new row IS cur),
// paired with keep = fOld carried from iter s-1. DS ops 28 -> 16/step; the
// serial DS dependency chain 14 -> 8/step.
//
// Correctness invariants (desk-verified):
//  - Halo history hLo/hLn[s] mirrors OB/MB[s] rows (t-s-2, t-s-1) at columns
//    gx-1 / gx+4; index 7 = f_7 history paired with OD/MD. Parity-swapped per
//    step exactly like OB/MB. Old-code equivalence:
//      erode edge:  min3(hLo,hLn,nL)  == shfl(min3(fOld,fMid,cur).w) (old lft)
//      dilate edge: max3(+-hLo,hLn,+-nL) == shfl(vx.w) (old dl), with the same
//      topOK/botOK row masks (top = t-s-2, bot = t-s for center t-s-1).
//  - term_{s-1}(t-s-1) accumulated at iter s into acc[7-s] (s=1..6) and the
//    post-loop f_7 dilate into acc[0]: same rows, same slots, same emission
//    step t = r+8 as the old code.
//  - y0 = 32k keeps t0 = y0-8 even -> parity mapping of pf/skpf slots holds.
//  - synthetic BIG rows (warm-up/OOB) are harmless in min chains and masked
//    to -BIG in dilate maxes via wave-uniform row conditionals.
//  - halos exactly tight: 8 rows warm-up, 8 cols/side shrink; bands own
//    disjoint column ranges {[0,248),[248,488),[488,728),[728,968),
//    [968,1024)} so the skel read-modify-write never races.

static constexpr int W = 1024, H = 1024, NIMG = 16;
static constexpr int RCH = 32;           // output rows per wave
static constexpr int NSTEP = RCH + 16;   // sweep steps (8 warm-up + 8 drain)
static constexpr float BIG = 3.0e38f;

__device__ __forceinline__ float min3f(float a, float b, float c) { return fminf(fminf(a, b), c); }
__device__ __forceinline__ float max3f(float a, float b, float c) { return fmaxf(fmaxf(a, b), c); }

template<bool FIRST, bool WRITE_E, int PFI>
__device__ __forceinline__
void pipe_step(int t, int y0, int lane, int gx,
               bool leftEdge, bool rightEdge, bool lane_ok,
               const float* __restrict__ in, float* __restrict__ eo,
               float* __restrict__ sk,
               float4 (&OB)[7], float4 (&MB)[7], float4& OD, float4& MD,
               float (&hLo)[8], float (&hLn)[8], float (&hRo)[8], float (&hRn)[8],
               float4 (&acc)[8], float4 (&pf)[2], float4 (&skpf)[2])
{
    // consume input row t (OOB rows are +BIG: erode identity)
    float4 cur;
    if ((unsigned)t < (unsigned)H) cur = pf[PFI];
    else                           cur = make_float4(BIG, BIG, BIG, BIG);
    // prefetch input row t+2 into the slot just consumed
    {
        const int nr = t + 2;
        if ((unsigned)nr < (unsigned)H && nr <= y0 + RCH + 7)
            pf[PFI] = *(const float4*)&in[(size_t)nr * W + gx];
    }

    float4 keep;   // f_{s-1}(t-s-1), carried from the previous iteration

#pragma unroll
    for (int s = 0; s < 7; ++s) {
        // invariant at entry: OB[s] = f_s(t-s-2), MB[s] = f_s(t-s-1),
        // cur = f_s(t-s); hLo[s]/hLn[s] = same two buffered rows @ col gx-1,
        // hRo[s]/hRn[s] @ col gx+4.
        const float4 fOld = OB[s];
        const float4 fMid = MB[s];

        // raw new-row halos (the ONLY cross-lane traffic for this stage)
        const float nL = __shfl(cur.w, lane - 1);   // f_s(t-s) @ gx-1 (lane 0: garbage)
        const float nR = __shfl(cur.x, lane + 1);   // f_s(t-s) @ gx+4 (lane 63: garbage)

        // ---- dilate of f_s centered at row t-s-1 (term for stage s-1) ----
        if (s >= 1) {
            const bool topOK = (t - s - 2) >= 0;   // row t-s-2 in-image?
            const bool botOK = (t - s) < H;        // row t-s   in-image?
            float4 vx;
            vx.x = max3f(topOK ? fOld.x : -BIG, fMid.x, botOK ? cur.x : -BIG);
            vx.y = max3f(topOK ? fOld.y : -BIG, fMid.y, botOK ? cur.y : -BIG);
            vx.z = max3f(topOK ? fOld.z : -BIG, fMid.z, botOK ? cur.z : -BIG);
            vx.w = max3f(topOK ? fOld.w : -BIG, fMid.w, botOK ? cur.w : -BIG);
            float vxL = max3f(topOK ? hLo[s] : -BIG, hLn[s], botOK ? nL : -BIG);
            float vxR = max3f(topOK ? hRo[s] : -BIG, hRn[s], botOK ? nR : -BIG);
            if (leftEdge)  vxL = -BIG;             // true image border clamp
            if (rightEdge) vxR = -BIG;
            float4 dn;
            dn.x = max3f(vxL,  vx.x, vx.y);
            dn.y = max3f(vx.x, vx.y, vx.z);
            dn.z = max3f(vx.y, vx.z, vx.w);
            dn.w = max3f(vx.z, vx.w, vxR);
            // term_{s-1}(t-s-1) = f_{s-1}(t-s-1) - dn ; FIFO slot 7-s
            acc[7 - s].x += keep.x - dn.x;
            acc[7 - s].y += keep.y - dn.y;
            acc[7 - s].z += keep.z - dn.z;
            acc[7 - s].w += keep.w - dn.w;
        }

        // ---- erode: en = f_{s+1}(t-s-1) ----
        float4 vm;
        vm.x = min3f(fOld.x, fMid.x, cur.x);
        vm.y = min3f(fOld.y, fMid.y, cur.y);
        vm.z = min3f(fOld.z, fMid.z, cur.z);
        vm.w = min3f(fOld.w, fMid.w, cur.w);
        float vmL = min3f(hLo[s], hLn[s], nL);
        float vmR = min3f(hRo[s], hRn[s], nR);
        if (leftEdge)  vmL = BIG;                  // true image border clamp
        if (rightEdge) vmR = BIG;
        float4 en;
        en.x = min3f(vmL,  vm.x, vm.y);
        en.y = min3f(vm.x, vm.y, vm.z);
        en.z = min3f(vm.y, vm.z, vm.w);
        en.w = min3f(vm.z, vm.w, vmR);

        if (s == 6 && WRITE_E) {
            const int er = t - 7;                  // en = f_7(t-7)
            if (er >= y0 && er < y0 + RCH && lane_ok)
                *(float4*)&eo[(size_t)er * W + gx] = en;
        }

        // rotate histories (old-role slots receive the newest row: parity swap)
        keep   = fOld;       // f_s(t-s-2) = f_s(t-(s+1)-1), for iter s+1's term
        OB[s]  = cur;
        hLo[s] = nL;
        hRo[s] = nR;
        cur = en;            // becomes f_{s+1}(t-(s+1)) for the next stage
    }

    // ---- stage-7 dilate centered at row t-8 (term for stage 6) ----
    {
        // cur = f_7(t-7); OD = f_7(t-9), MD = f_7(t-8); halos at index 7.
        const float nL7 = __shfl(cur.w, lane - 1);
        const float nR7 = __shfl(cur.x, lane + 1);
        const bool topOK = (t - 9) >= 0;
        const bool botOK = (t - 7) < H;
        float4 vx;
        vx.x = max3f(topOK ? OD.x : -BIG, MD.x, botOK ? cur.x : -BIG);
        vx.y = max3f(topOK ? OD.y : -BIG, MD.y, botOK ? cur.y : -BIG);
        vx.z = max3f(topOK ? OD.z : -BIG, MD.z, botOK ? cur.z : -BIG);
        vx.w = max3f(topOK ? OD.w : -BIG, MD.w, botOK ? cur.w : -BIG);
        float vxL = max3f(topOK ? hLo[7] : -BIG, hLn[7], botOK ? nL7 : -BIG);
        float vxR = max3f(topOK ? hRo[7] : -BIG, hRn[7], botOK ? nR7 : -BIG);
        if (leftEdge)  vxL = -BIG;
        if (rightEdge) vxR = -BIG;
        float4 dn;
        dn.x = max3f(vxL,  vx.x, vx.y);
        dn.y = max3f(vx.x, vx.y, vx.z);
        dn.z = max3f(vx.y, vx.z, vx.w);
        dn.w = max3f(vx.z, vx.w, vxR);
        // keep = f_6(t-8) from iter 6
        acc[0].x += keep.x - dn.x;
        acc[0].y += keep.y - dn.y;
        acc[0].z += keep.z - dn.z;
        acc[0].w += keep.w - dn.w;
        OD     = cur;        // f_7(t-7) into old-role slot (parity swap)
        hLo[7] = nL7;
        hRo[7] = nR7;
    }

    // ---- emit completed row t-8 ----
    if (t >= y0 + 8) {
        const int r = t - 8;
        float4 v = acc[0];
        if (!FIRST) {
            const float4 o = skpf[PFI];        // skel row t-8, prefetched at step t-2
            v.x += o.x; v.y += o.y; v.z += o.z; v.w += o.w;
        }
        if (lane_ok)
            *(float4*)&sk[(size_t)r * W + gx] = v;
    }
#pragma unroll
    for (int j = 0; j < 7; ++j) acc[j] = acc[j + 1];
    acc[7] = make_float4(0.f, 0.f, 0.f, 0.f);

    // ---- prefetch old skel row t-6 AFTER emission (consumed at step t+2,
    //      which shares this step's parity and thus this PFI slot) ----
    if (!FIRST) {
        const int pr = t - 6;
        if (pr >= y0 && pr < y0 + RCH)
            skpf[PFI] = *(const float4*)&sk[(size_t)pr * W + gx];
    }
}

template<bool FIRST, bool WRITE_E>
__global__ __launch_bounds__(64)
void skel_pipe(const float* __restrict__ ein, float* __restrict__ eout,
               float* __restrict__ skel)
{
    const int lane = threadIdx.x;          // one wave per block
    const int bx = blockIdx.x;             // band 0..4
    const int y0 = blockIdx.y * RCH;       // row chunk
    const int img = blockIdx.z;
    const int x0 = (bx == 4) ? 768 : bx * 240;   // last band starts at 1024-256
    const int gx = x0 + 4 * lane;                // gx max = 768 + 252 = 1020

    const size_t base = (size_t)img * (size_t)(W * H);
    const float* __restrict__ in = ein + base;
    float* __restrict__ eo = eout + base;
    float* __restrict__ sk = skel + base;

    const bool leftEdge  = (gx == 0);
    const bool rightEdge = (gx + 4 == W);
    // disjoint write ownership (bands overlap in compute, never in writes)
    const int own_lo = (bx == 0) ? 0 : ((bx == 4) ? 968 : x0 + 8);
    const int own_hi = (bx == 4) ? W : x0 + 248;
    const bool lane_ok = (gx >= own_lo) && (gx < own_hi);

    float4 B0[7], B1[7], D0, D1, acc[8], pf[2], skpf[2];
    float hA_L[8], hB_L[8], hA_R[8], hB_R[8];
    const float4 big4 = make_float4(BIG, BIG, BIG, BIG);
    const float4 z4   = make_float4(0.f, 0.f, 0.f, 0.f);
#pragma unroll
    for (int s = 0; s < 7; ++s) { B0[s] = big4; B1[s] = big4; }
    D0 = big4; D1 = big4;
#pragma unroll
    for (int s = 0; s < 8; ++s) { hA_L[s] = BIG; hB_L[s] = BIG; hA_R[s] = BIG; hB_R[s] = BIG; }
#pragma unroll
    for (int j = 0; j < 8; ++j) acc[j] = z4;
    pf[0] = big4; pf[1] = big4; skpf[0] = z4; skpf[1] = z4;

    // prefetch input rows t0, t0+1
    {
        const int r0 = y0 - 8, r1 = y0 - 7;
        if (r0 >= 0) pf[0] = *(const float4*)&in[(size_t)r0 * W + gx];
        if (r1 >= 0) pf[1] = *(const float4*)&in[(size_t)r1 * W + gx];
    }

    const int t0 = y0 - 8;   // even (y0 multiple of 32) -> parity mapping holds
#pragma unroll 1
    for (int t = t0; t < t0 + NSTEP; t += 2) {
        pipe_step<FIRST, WRITE_E, 0>(t,     y0, lane, gx, leftEdge, rightEdge, lane_ok,
                                     in, eo, sk, B0, B1, D0, D1,
                                     hA_L, hB_L, hA_R, hB_R, acc, pf, skpf);
        pipe_step<FIRST, WRITE_E, 1>(t + 1, y0, lane, gx, leftEdge, rightEdge, lane_ok,
                                     in, eo, sk, B1, B0, D1, D0,
                                     hB_L, hA_L, hB_R, hA_R, acc, pf, skpf);
    }
}

extern "C" void kernel_launch(void* const* d_in, const int* in_sizes, int n_in,
                              void* d_out, int out_size, void* d_ws, size_t ws_size,
                              hipStream_t stream)
{
    const float* x = (const float*)d_in[0];
    float* skel = (float*)d_out;
    const size_t n = (size_t)NIMG * W * H;

    float* e0 = (float*)d_ws;
    float* e1 = e0 + n;

    dim3 grid(5, H / RCH, NIMG);
    dim3 block(64);

    // steps 0-6: x -> e0 ; 7-13: e0 -> e1 ; 14-20: e1 -> (none)
    skel_pipe<true,  true ><<<grid, block, 0, stream>>>(x,  e0, skel);
    skel_pipe<false, true ><<<grid, block, 0, stream>>>(e0, e1, skel);
    skel_pipe<false, false><<<grid, block, 0, stream>>>(e1, e0, skel);
}

// Round 3
// 361.579 us; speedup vs baseline: 1.3373x; 1.3373x over previous
//
#include <hip/hip_runtime.h>

// Morphological skeleton, 16 x 1024 x 1024 f32.
// skel = sum_{k=0..20} ( e_k - dilate3x3(e_{k+1}) ),  e_0 = x, e_{k+1} = erode3x3(e_k)
// (reduce_window SAME semantics: windows clamp at image borders).
//
// Register-resident vertical pipeline, zero LDS tile. 3 dispatches x G=7 fused
// erosion stages. One wave (64 lanes x float4) owns a 256-col band and sweeps
// RCH+16 rows (RCH output + warm-up/drain). Per stage: 2-row register buffer
// (parity-swapped); erode = v_min3 vertical + shfl lane+-1 horizontal; dilate
// of f_{s+1} reuses stage s+1's buffers (read before their update); terms go
// into an 8-deep register FIFO, emitted as rows complete.
//
// Round-7 changes vs round 5/6: round 6 (halo-register scheme, -43% DS +35%
// VALU) was 38% SLOWER at unchanged VALUBusy~45% => time tracks VALU count at
// a pinned ~45-49% duty; DS-throughput model falsified. Round 5 also showed
// duty rises only with work, not wave count, and Occupancy=15% revealed only
// ~1.2 waves/SIMD RESIDENT from single-wave workgroups. So:
//  (a) revert to the round-5 inner loop (proven 109 us/dispatch formulation);
//  (b) pack 4 waves per workgroup (block 64x4; each wave = private row-chunk,
//      no LDS/sync) to lift residency per CU;
//  (c) EDGE template specialization: interior chunks (32 <= y0 <= 960, 30/32)
//      fold topOK/botOK to constant-true, deleting 56 cndmask/step.
//
// Correctness invariants (desk-verified):
//  - interior test: topOK=(t-s-3>=0) min at t0-9 = y0-17 >= 0 iff y0>=32;
//    botOK=(t-s-1<H) max at y0+38 < 1024 iff y0<=960. EDGE=true path is
//    byte-identical behavior to round 5 for the 2 boundary chunks.
//  - y0 = 32k keeps t0 = y0-8 even -> parity mapping of pf/skpf slots holds.
//  - synthetic erode values at OOB/warm-up rows are >= the true clamped
//    erosion (dependency-cone subset) => harmless in the min chain; masked to
//    -BIG in the dilate max via wave-uniform row conditionals (EDGE path).
//  - halos exactly tight: 8 rows warm-up (t0 = y0-8), 8 cols/side shrink;
//    bands own disjoint column ranges {[0,248),[248,488),[488,728),[728,968),
//    [968,1024)} so the skel read-modify-write never races.

static constexpr int W = 1024, H = 1024, NIMG = 16;
static constexpr int RCH = 32;           // output rows per wave
static constexpr int NSTEP = RCH + 16;   // sweep steps (8 warm-up + 8 drain)
static constexpr int WPB = 4;            // waves per workgroup
static constexpr float BIG = 3.0e38f;

__device__ __forceinline__ float min3f(float a, float b, float c) { return fminf(fminf(a, b), c); }
__device__ __forceinline__ float max3f(float a, float b, float c) { return fmaxf(fmaxf(a, b), c); }

template<bool FIRST, bool WRITE_E, bool EDGE, int PFI>
__device__ __forceinline__
void pipe_step(int t, int y0, int lane, int gx,
               bool leftEdge, bool rightEdge, bool lane_ok,
               const float* __restrict__ in, float* __restrict__ eo,
               float* __restrict__ sk,
               float4 (&OB)[7], float4 (&MB)[7], float4& OD, float4& MD,
               float4 (&acc)[8], float4 (&pf)[2], float4 (&skpf)[2])
{
    // consume input row t (OOB rows are +BIG: erode identity; interior: always in-image)
    float4 cur;
    if (!EDGE || (unsigned)t < (unsigned)H) cur = pf[PFI];
    else                                    cur = make_float4(BIG, BIG, BIG, BIG);
    // prefetch input row t+2 into the slot just consumed
    {
        const int nr = t + 2;
        if ((!EDGE || (unsigned)nr < (unsigned)H) && nr <= y0 + RCH + 7)
            pf[PFI] = *(const float4*)&in[(size_t)nr * W + gx];
    }

#pragma unroll
    for (int s = 0; s < 7; ++s) {
        // invariant at entry: OB[s] = f_s(t-s-2), MB[s] = f_s(t-s-1),
        // cur = f_s(t-s) (produced this step by the previous stage / load).
        const float4 fOld = OB[s];
        const float4 fMid = MB[s];

        // ---- erode: en = f_{s+1}(t-s-1) ----
        float4 vm;
        vm.x = min3f(fOld.x, fMid.x, cur.x);
        vm.y = min3f(fOld.y, fMid.y, cur.y);
        vm.z = min3f(fOld.z, fMid.z, cur.z);
        vm.w = min3f(fOld.w, fMid.w, cur.w);
        float lft = __shfl(vm.w, lane - 1);   // lane 0: garbage -> invalid cols
        float rgt = __shfl(vm.x, lane + 1);   // lane 63: garbage -> invalid cols
        if (leftEdge)  lft = BIG;             // true image border clamp
        if (rightEdge) rgt = BIG;
        float4 en;
        en.x = min3f(lft,  vm.x, vm.y);
        en.y = min3f(vm.x, vm.y, vm.z);
        en.z = min3f(vm.y, vm.z, vm.w);
        en.w = min3f(vm.z, vm.w, rgt);

        OB[s] = cur;   // old-role slot receives newest f_s row (parity swap)

        // ---- dilate of f_{s+1} centered at row t-s-2 ----
        // gOld/gMid from stage s+1's buffers, read BEFORE their update in
        // iteration s+1 of this same step.
        float4 gOld, gMid;
        if (s < 6) { gOld = OB[s + 1]; gMid = MB[s + 1]; }  // f_{s+1}(t-s-3), (t-s-2)
        else       { gOld = OD;        gMid = MD;        }
        const bool topOK = !EDGE || ((t - s - 3) >= 0);   // row t-s-3 in-image?
        const bool botOK = !EDGE || ((t - s - 1) < H);    // row t-s-1 in-image?
        float4 vx;
        {
            float txx = topOK ? gOld.x : -BIG, bxx = botOK ? en.x : -BIG;
            float txy = topOK ? gOld.y : -BIG, bxy = botOK ? en.y : -BIG;
            float txz = topOK ? gOld.z : -BIG, bxz = botOK ? en.z : -BIG;
            float txw = topOK ? gOld.w : -BIG, bxw = botOK ? en.w : -BIG;
            vx.x = max3f(txx, gMid.x, bxx);
            vx.y = max3f(txy, gMid.y, bxy);
            vx.z = max3f(txz, gMid.z, bxz);
            vx.w = max3f(txw, gMid.w, bxw);
        }
        float dl = __shfl(vx.w, lane - 1);
        float dr = __shfl(vx.x, lane + 1);
        if (leftEdge)  dl = -BIG;
        if (rightEdge) dr = -BIG;
        float4 dn;
        dn.x = max3f(dl,   vx.x, vx.y);
        dn.y = max3f(vx.x, vx.y, vx.z);
        dn.z = max3f(vx.y, vx.z, vx.w);
        dn.w = max3f(vx.z, vx.w, dr);

        // term_s(t-s-2) = f_s(t-s-2) - dilate(f_{s+1})(t-s-2); FIFO slot 6-s
        acc[6 - s].x += fOld.x - dn.x;
        acc[6 - s].y += fOld.y - dn.y;
        acc[6 - s].z += fOld.z - dn.z;
        acc[6 - s].w += fOld.w - dn.w;

        if (s == 6) {
            if (WRITE_E) {
                const int er = t - 7;          // en = f_7(t-7)
                if (er >= y0 && er < y0 + RCH && lane_ok)
                    *(float4*)&eo[(size_t)er * W + gx] = en;
            }
            OD = en;
        }
        cur = en;   // becomes f_{s+1}(t-(s+1)) for the next stage
    }

    // ---- emit completed row t-8 ----
    if (t >= y0 + 8) {
        const int r = t - 8;
        float4 v = acc[0];
        if (!FIRST) {
            const float4 o = skpf[PFI];        // skel row t-8, prefetched at step t-2
            v.x += o.x; v.y += o.y; v.z += o.z; v.w += o.w;
        }
        if (lane_ok)
            *(float4*)&sk[(size_t)r * W + gx] = v;
    }
#pragma unroll
    for (int j = 0; j < 7; ++j) acc[j] = acc[j + 1];
    acc[7] = make_float4(0.f, 0.f, 0.f, 0.f);

    // ---- prefetch old skel row t-6 AFTER emission (consumed at step t+2,
    //      which shares this step's parity and thus this PFI slot) ----
    if (!FIRST) {
        const int pr = t - 6;
        if (pr >= y0 && pr < y0 + RCH)
            skpf[PFI] = *(const float4*)&sk[(size_t)pr * W + gx];
    }
}

template<bool FIRST, bool WRITE_E, bool EDGE>
__device__ __forceinline__
void sweep(int y0, int lane, int gx,
           bool leftEdge, bool rightEdge, bool lane_ok,
           const float* __restrict__ in, float* __restrict__ eo,
           float* __restrict__ sk)
{
    float4 B0[7], B1[7], D0, D1, acc[8], pf[2], skpf[2];
    const float4 big4 = make_float4(BIG, BIG, BIG, BIG);
    const float4 z4   = make_float4(0.f, 0.f, 0.f, 0.f);
#pragma unroll
    for (int s = 0; s < 7; ++s) { B0[s] = big4; B1[s] = big4; }
    D0 = big4; D1 = big4;
#pragma unroll
    for (int j = 0; j < 8; ++j) acc[j] = z4;
    pf[0] = big4; pf[1] = big4; skpf[0] = z4; skpf[1] = z4;

    // prefetch input rows t0, t0+1 (interior: always in-image)
    {
        const int r0 = y0 - 8, r1 = y0 - 7;
        if (!EDGE || r0 >= 0) pf[0] = *(const float4*)&in[(size_t)r0 * W + gx];
        if (!EDGE || r1 >= 0) pf[1] = *(const float4*)&in[(size_t)r1 * W + gx];
    }

    const int t0 = y0 - 8;   // even (y0 multiple of 32) -> parity mapping holds
#pragma unroll 1
    for (int t = t0; t < t0 + NSTEP; t += 2) {
        pipe_step<FIRST, WRITE_E, EDGE, 0>(t,     y0, lane, gx, leftEdge, rightEdge, lane_ok,
                                           in, eo, sk, B0, B1, D0, D1, acc, pf, skpf);
        pipe_step<FIRST, WRITE_E, EDGE, 1>(t + 1, y0, lane, gx, leftEdge, rightEdge, lane_ok,
                                           in, eo, sk, B1, B0, D1, D0, acc, pf, skpf);
    }
}

template<bool FIRST, bool WRITE_E>
__global__ __launch_bounds__(WPB * 64)
void skel_pipe(const float* __restrict__ ein, float* __restrict__ eout,
               float* __restrict__ skel)
{
    const int lane = threadIdx.x;          // 64 lanes; threadIdx.y selects the wave
    const int bx = blockIdx.x;             // band 0..4
    const int y0 = (blockIdx.y * WPB + (int)threadIdx.y) * RCH;  // private row chunk
    const int img = blockIdx.z;
    const int x0 = (bx == 4) ? 768 : bx * 240;   // last band starts at 1024-256
    const int gx = x0 + 4 * lane;                // gx max = 768 + 252 = 1020

    const size_t base = (size_t)img * (size_t)(W * H);
    const float* __restrict__ in = ein + base;
    float* __restrict__ eo = eout + base;
    float* __restrict__ sk = skel + base;

    const bool leftEdge  = (gx == 0);
    const bool rightEdge = (gx + 4 == W);
    // disjoint write ownership (bands overlap in compute, never in writes)
    const int own_lo = (bx == 0) ? 0 : ((bx == 4) ? 968 : x0 + 8);
    const int own_hi = (bx == 4) ? W : x0 + 248;
    const bool lane_ok = (gx >= own_lo) && (gx < own_hi);

    // interior: all topOK/botOK masks constant-true (see header proof)
    if (y0 >= 32 && y0 <= H - RCH - 32)
        sweep<FIRST, WRITE_E, false>(y0, lane, gx, leftEdge, rightEdge, lane_ok, in, eo, sk);
    else
        sweep<FIRST, WRITE_E, true >(y0, lane, gx, leftEdge, rightEdge, lane_ok, in, eo, sk);
}

extern "C" void kernel_launch(void* const* d_in, const int* in_sizes, int n_in,
                              void* d_out, int out_size, void* d_ws, size_t ws_size,
                              hipStream_t stream)
{
    const float* x = (const float*)d_in[0];
    float* skel = (float*)d_out;
    const size_t n = (size_t)NIMG * W * H;

    float* e0 = (float*)d_ws;
    float* e1 = e0 + n;

    dim3 grid(5, H / (RCH * WPB), NIMG);
    dim3 block(64, WPB);

    // steps 0-6: x -> e0 ; 7-13: e0 -> e1 ; 14-20: e1 -> (none)
    skel_pipe<true,  true ><<<grid, block, 0, stream>>>(x,  e0, skel);
    skel_pipe<false, true ><<<grid, block, 0, stream>>>(e0, e1, skel);
    skel_pipe<false, false><<<grid, block, 0, stream>>>(e1, e0, skel);
}